// Round 14
// baseline (5986.487 us; speedup 1.0000x reference)
//
#include <hip/hip_runtime.h>

// Problem constants (from reference): B=32, T=2048, D_IN=D_OUT=512, fp32.
constexpr int B = 32, T = 2048, D = 512;

typedef float f32x4 __attribute__((ext_vector_type(4)));

// ---------------- Kernel 1: xw = x @ W + b, written in-place into d_out ----
__global__ __launch_bounds__(256) void xw_gemm(
    const float* __restrict__ A, const float* __restrict__ W,
    const float* __restrict__ bias, float* __restrict__ C) {
  __shared__ float As[16][68];
  __shared__ float Bs[16][68];
  const int tid = threadIdx.x;
  const int M0 = blockIdx.y * 64, N0 = blockIdx.x * 64;
  const int tn = tid & 15, tm = tid >> 4;
  const int rA = tid >> 2, kA = (tid & 3) << 2;
  const int kB = tid >> 4, nB = (tid & 15) << 2;
  float acc[4][4] = {};
  for (int k0 = 0; k0 < 512; k0 += 16) {
    float4 a4 = *(const float4*)&A[(size_t)(M0 + rA) * 512 + k0 + kA];
    As[kA + 0][rA] = a4.x;
    As[kA + 1][rA] = a4.y;
    As[kA + 2][rA] = a4.z;
    As[kA + 3][rA] = a4.w;
    *(float4*)&Bs[kB][nB] = *(const float4*)&W[(size_t)(k0 + kB) * 512 + N0 + nB];
    __syncthreads();
#pragma unroll
    for (int k = 0; k < 16; ++k) {
      float a0 = As[k][tm * 4 + 0], a1 = As[k][tm * 4 + 1];
      float a2 = As[k][tm * 4 + 2], a3 = As[k][tm * 4 + 3];
      float b0 = Bs[k][tn * 4 + 0], b1 = Bs[k][tn * 4 + 1];
      float b2 = Bs[k][tn * 4 + 2], b3 = Bs[k][tn * 4 + 3];
      acc[0][0] += a0 * b0; acc[0][1] += a0 * b1; acc[0][2] += a0 * b2; acc[0][3] += a0 * b3;
      acc[1][0] += a1 * b0; acc[1][1] += a1 * b1; acc[1][2] += a1 * b2; acc[1][3] += a1 * b3;
      acc[2][0] += a2 * b0; acc[2][1] += a2 * b1; acc[2][2] += a2 * b2; acc[2][3] += a2 * b3;
      acc[3][0] += a3 * b0; acc[3][1] += a3 * b1; acc[3][2] += a3 * b2; acc[3][3] += a3 * b3;
    }
    __syncthreads();
  }
#pragma unroll
  for (int i = 0; i < 4; ++i) {
    const size_t row = (size_t)(M0 + tm * 4 + i);
    float4 v;
    v.x = acc[i][0] + bias[N0 + tn * 4 + 0];
    v.y = acc[i][1] + bias[N0 + tn * 4 + 1];
    v.z = acc[i][2] + bias[N0 + tn * 4 + 2];
    v.w = acc[i][3] + bias[N0 + tn * 4 + 3];
    *(float4*)&C[row * 512 + N0 + tn * 4] = v;
  }
}

// ---------------- Kernel 2: single-wave poller + LDS-flag broadcast --------
// 256 blocks x 512 thr = 32 cliques (one per batch) x 8 blocks (64 cols).
// Wave 0 alone polls the clique slab: 2x dwordx4/lane = full 512 floats in
// 2 VMEM instrs; band-check 8 vals/lane + __all. On success: LDS write
// (swizzled) -> threadfence_block -> LDS flag = r. Waves 1-7 spin the flag
// (pure LDS, ~30cy granularity), ds_read slices, compute. NO __syncthreads
// in the loop. Counted waits (wave-level, uniform hit/miss):
//   wave0 stream [A2][st2][xw]: entry vmcnt(3), pre-tanh vmcnt(2)
//   waves1-7 stream [st2][xw]:  pre-tanh vmcnt(0) (acks 1 step old, free)
// Transport: sc1 band self-tagging (proven r2..r13). W in regs (r13 fix).
constexpr int NBLK = 256, NTHR = 512;

__device__ __forceinline__ float mytanh(float x) {
  const float xc = fminf(fmaxf(x, -9.0f), 9.0f);
  const float t = __builtin_amdgcn_exp2f(xc * 2.885390081777927f);  // e^(2x)
  return 1.0f - 2.0f / (t + 1.0f);
}
__device__ __forceinline__ void ivld4_sc1(const float* p, f32x4& v) {
  asm volatile("global_load_dwordx4 %0, %1, off sc1" : "=&v"(v) : "v"(p) : "memory");
}
__device__ __forceinline__ void ivld4(const float* p, f32x4& v) {
  asm volatile("global_load_dwordx4 %0, %1, off" : "=&v"(v) : "v"(p) : "memory");
}
__device__ __forceinline__ void ivst4(float* p, f32x4 v) {
  asm volatile("global_store_dwordx4 %0, %1, off" ::"v"(p), "v"(v) : "memory");
}
__device__ __forceinline__ void ivst4_sc1(float* p, f32x4 v) {
  asm volatile("global_store_dwordx4 %0, %1, off sc1" ::"v"(p), "v"(v) : "memory");
}
__device__ __forceinline__ int chk4(f32x4 v, float off) {
  return (fabsf(v[0] - off) < 1.5f) & (fabsf(v[1] - off) < 1.5f) &
         (fabsf(v[2] - off) < 1.5f) & (fabsf(v[3] - off) < 1.5f);
}

__global__ __launch_bounds__(NTHR)
__attribute__((amdgpu_waves_per_eu(2, 2)))
void rnn_scan(float* __restrict__ out, const float* __restrict__ Wrec,
              float* __restrict__ xbuf) {
  __shared__ float hs[2][512];  // h, parity double-buffered, XOR-swizzled
  __shared__ int flag;          // last step broadcast by wave 0
  const int blk = blockIdx.x;
  const int batch = blk >> 3, cg = blk & 7;
  const int tid = threadIdx.x;
  const int wvi = tid >> 6, lane = tid & 63;
  const int kq = tid & 31, cp = tid >> 5;
  const int k0 = kq * 16;
  const int col0 = cg * 64 + cp * 4;
  const int swz = (kq & 7) << 2;
  const bool w0 = (wvi == 0);
  const bool pub = (kq == 0);

  if (tid == 0) flag = 0;
  __syncthreads();  // prologue only — guards uninitialized flag

  // W slice into registers (remat-proof r13 path; call-free loop keeps it)
  f32x4 wreg[16];
#pragma unroll
  for (int i = 0; i < 16; ++i) ivld4(&Wrec[(size_t)(k0 + i) * D + col0], wreg[i]);
  asm volatile("s_waitcnt vmcnt(0)" ::: "memory");

  float* slab = xbuf + (size_t)batch * 1024;  // [parity(2)][512]
  float* op = out + (size_t)batch * T * D;
  const int kA = 4 * lane, kB = 256 + 4 * lane;      // wave0 poll coverage
  const int iA = kA ^ (((kA >> 4) & 7) << 2);        // swizzled LDS indices
  const int iB = kB ^ (((kB >> 4) & 7) << 2);

  f32x4 xw4 = {0, 0, 0, 0}, pA0, pA1;
  // ---- t = 0: h0 = tanh(xw_0); establish per-wave VMEM streams ----
  {
    f32x4 h0 = {0, 0, 0, 0};
    if (pub) {
      const f32x4 x0 = *(const f32x4*)&op[col0];  // plain; waited at use
      h0[0] = mytanh(x0[0]); h0[1] = mytanh(x0[1]);
      h0[2] = mytanh(x0[2]); h0[3] = mytanh(x0[3]);
    }
    if (w0) {  // pre-issue poll for r=1 (parity 0)
      ivld4_sc1(&slab[kA], pA0);
      ivld4_sc1(&slab[kB], pA1);
    }
    if (pub) {
      ivst4_sc1(&slab[col0], h0 + 3.0f);  // band off(0) = +3
      ivst4(&op[col0], h0);
      ivld4(&op[(size_t)D + col0], xw4);  // xw for r=1
    }
  }

  for (int r = 1; r < T; ++r) {
    const int pv = (r - 1) & 1, pw = r & 1;
    const int iR = (r - 1) & 3, iW = r & 3;
    const float offR = ((iR & 1) ? 9.f : 3.f) * ((iR & 2) ? -1.f : 1.f);
    const float offW = ((iW & 1) ? 9.f : 3.f) * ((iW & 2) ? -1.f : 1.f);

    if (w0) {
      // entry: outstanding [A2, st2, xw] -> vmcnt(3): A landed, never acks
      asm volatile("s_waitcnt vmcnt(3)" : "+v"(pA0), "+v"(pA1)::"memory");
      __builtin_amdgcn_sched_barrier(0);
      int ok = chk4(pA0, offR) & chk4(pA1, offR);
      if (!__all(ok)) {
        const float* s0 = &slab[pv * 512 + kA];
        const float* s1 = &slab[pv * 512 + kB];
        do {
          ivld4_sc1(s0, pA0);
          ivld4_sc1(s1, pA1);
          asm volatile("s_waitcnt vmcnt(0)" : "+v"(pA0), "+v"(pA1)::"memory");
          __builtin_amdgcn_sched_barrier(0);
          ok = chk4(pA0, offR) & chk4(pA1, offR);
        } while (!__all(ok));
      }
      // broadcast h to the block (swizzled), then release via LDS flag
      *(f32x4*)&hs[pv][iA] = pA0 - offR;
      *(f32x4*)&hs[pv][iB] = pA1 - offR;
      __threadfence_block();
      if (lane == 0) *(volatile int*)&flag = r;
      // pre-issue next poll (parity pw) — stale now, checked next entry
      ivld4_sc1(&slab[pw * 512 + kA], pA0);
      ivld4_sc1(&slab[pw * 512 + kB], pA1);
    } else {
      while (*(volatile int*)&flag < r) {}
      __builtin_amdgcn_sched_barrier(0);
    }

    // ---- compute: 4 cols x 16 k, W in regs, h from LDS ----
    f32x4 a = {0, 0, 0, 0};
#pragma unroll
    for (int i4 = 0; i4 < 4; ++i4) {
      const f32x4 h4 = *(const f32x4*)&hs[pv][(k0 + 4 * i4) ^ swz];
#pragma unroll
      for (int j = 0; j < 4; ++j) {
        const float hh = h4[j];
        a[0] += wreg[4 * i4 + j][0] * hh;
        a[1] += wreg[4 * i4 + j][1] * hh;
        a[2] += wreg[4 * i4 + j][2] * hh;
        a[3] += wreg[4 * i4 + j][3] * hh;
      }
    }
#pragma unroll
    for (int m = 1; m < 32; m <<= 1) {
      a[0] += __shfl_xor(a[0], m);
      a[1] += __shfl_xor(a[1], m);
      a[2] += __shfl_xor(a[2], m);
      a[3] += __shfl_xor(a[3], m);
    }

    // ---- finalize + publish (pub lanes; band store FIRST = earliest) ----
    if (pub) {
      if (w0)
        asm volatile("s_waitcnt vmcnt(2)" : "+v"(xw4)::"memory");  // xw only
      else
        asm volatile("s_waitcnt vmcnt(0)" : "+v"(xw4)::"memory");  // acks old
      __builtin_amdgcn_sched_barrier(0);
      f32x4 h;
      h[0] = mytanh(a[0] + xw4[0]);
      h[1] = mytanh(a[1] + xw4[1]);
      h[2] = mytanh(a[2] + xw4[2]);
      h[3] = mytanh(a[3] + xw4[3]);
      ivst4_sc1(&slab[pw * 512 + col0], h + offW);
      ivst4(&op[(size_t)r * D + col0], h);
      const int rn = (r + 1 < T) ? (r + 1) : r;
      ivld4(&op[(size_t)rn * D + col0], xw4);  // prefetch next xw
    }
  }
}

extern "C" void kernel_launch(void* const* d_in, const int* in_sizes, int n_in,
                              void* d_out, int out_size, void* d_ws, size_t ws_size,
                              hipStream_t stream) {
  const float* x = (const float*)d_in[0];
  const float* W = (const float*)d_in[1];
  const float* Wrec = (const float*)d_in[2];
  const float* bias = (const float*)d_in[3];
  float* out = (float*)d_out;

  // xw + bias straight into d_out (row = b*T+t matches [B][T][D]).
  xw_gemm<<<dim3(D / 64, (B * T) / 64), 256, 0, stream>>>(x, W, bias, out);

  // xbuf: 32 cliques x 2 parities x 512 floats = 128 KB. Zeroed every
  // launch (zero is in no band) -> deterministic replays.
  hipMemsetAsync(d_ws, 0, 131072, stream);
  float* xbuf = (float*)d_ws;

  void* args[] = {(void*)&out, (void*)&Wrec, (void*)&xbuf};
  hipLaunchCooperativeKernel(reinterpret_cast<void*>(rnn_scan), dim3(NBLK),
                             dim3(NTHR), args, 0, stream);
}